// Round 1
// 155.676 us; speedup vs baseline: 1.0075x; 1.0075x over previous
//
#include <hip/hip_runtime.h>
#include <climits>

#define VOCAB 1024
#define MAXC  4      // max backoff-chain length (MAX_ORDER); chain always ends at state 0
#define SLOT_SHIFT 8

__global__ __launch_bounds__(256)
void ngram_advance(const float* __restrict__ arcs_weights,
                   const float* __restrict__ backoff_weights,
                   const int*   __restrict__ to_states,
                   const int*   __restrict__ ilabels,
                   const int*   __restrict__ backoff_to_states,
                   const int*   __restrict__ state_start_arcs,
                   const int*   __restrict__ state_end_arcs,
                   const int*   __restrict__ states,
                   float* __restrict__ out_scores,
                   float* __restrict__ out_next)
{
    // Per-label override table: (level<<8)|slot, sentinel = INT_MAX.
    __shared__ int   tab[VOCAB];
    __shared__ float s_wt[64];            // staged arc weights, slot = l*16+j
    __shared__ int   s_to[64];            // staged arc targets
    __shared__ int   ch_state[MAXC], ch_sa[MAXC], ch_na[MAXC];
    __shared__ float ch_bwsum[MAXC];      // prefix sums of backoff weights (chain order)
    __shared__ int   ch_len;

    const int b   = blockIdx.x;
    const int tid = threadIdx.x;

    // vectorized sentinel init: 256 threads x int4 = 1024 entries (ds_write_b128)
    reinterpret_cast<int4*>(tab)[tid] = make_int4(INT_MAX, INT_MAX, INT_MAX, INT_MAX);

    // thread 0: walk the per-row, label-independent backoff chain.
    // Orders strictly decrease along the chain, so it always terminates at
    // state 0 within MAXC steps; state 0's arcs are exactly arange(V).
    // Critical path is 1 dependent load (backoff_to_states) per level.
    if (tid == 0) {
        int cur = states[b];
        int len = 0;
        float acc = 0.f;
        for (;;) {
            int sa = state_start_arcs[cur];
            ch_state[len] = cur;
            ch_sa[len]    = sa;
            ch_na[len]    = state_end_arcs[cur] - sa;
            ch_bwsum[len] = acc;                    // sum of bw over levels < len
            acc += backoff_weights[cur];            // chain-order accumulation == reference
            ++len;
            if (cur == 0 || len == MAXC) break;
            cur = backoff_to_states[cur];
        }
        ch_len = len;
    }
    __syncthreads();

    const int   len    = ch_len;
    const int   last   = len - 1;          // chain's last level is state 0
    const float bwlast = ch_bwsum[last];
    const int   sa0    = ch_sa[last];
    const int   v0     = tid << 2;         // 4 consecutive labels per thread

    // HOISTED fallback loads (state-0 arc block, same 8 KB for every block ->
    // L1/L2-hot after first touch). Issued before the scatter + barrier so the
    // load latency hides under them instead of serializing after barrier 2.
    // sa0 == state_start_arcs[0] == 0 by construction -> 16B-aligned; keep a
    // uniform-branch scalar fallback in case it isn't.
    float aw[4]; int tg[4];
    if ((sa0 & 3) == 0) {
        const float4 a4 = *reinterpret_cast<const float4*>(arcs_weights + sa0 + v0);
        const int4   t4 = *reinterpret_cast<const int4*>(to_states    + sa0 + v0);
        aw[0] = a4.x; aw[1] = a4.y; aw[2] = a4.z; aw[3] = a4.w;
        tg[0] = t4.x; tg[1] = t4.y; tg[2] = t4.z; tg[3] = t4.w;
    } else {
        #pragma unroll
        for (int j = 0; j < 4; ++j) {
            aw[j] = arcs_weights[sa0 + v0 + j];
            tg[j] = to_states[sa0 + v0 + j];
        }
    }

    // Scatter the <=30 non-start arcs into the label table.
    // atomicMin keeps the EARLIEST level (reference: first found wins).
    // Labels are strictly increasing within a level -> no intra-level dups.
    if (tid < 64) {
        int l = tid >> 4, j = tid & 15;
        if (l < len && ch_state[l] != 0 && j < ch_na[l]) {
            int a = ch_sa[l] + j;
            s_wt[tid] = arcs_weights[a];
            s_to[tid] = to_states[a];
            atomicMin(&tab[ilabels[a]], (l << SLOT_SHIFT) | tid);
        }
    }
    __syncthreads();

    // Single-pass vectorized gather: ds_read_b128 of the table, register
    // combine, float4 stores. Non-start hits (<3%): prefix-bw + staged wt/to.
    const int4 t4 = *reinterpret_cast<const int4*>(&tab[v0]);
    const int  tv[4] = { t4.x, t4.y, t4.z, t4.w };
    float sc[4], nx[4];
    #pragma unroll
    for (int j = 0; j < 4; ++j) {
        const int t  = tv[j];
        const int fl = t >> SLOT_SHIFT;    // sentinel -> huge -> fallback
        if (fl < last) {
            const int slot = t & 255;
            sc[j] = ch_bwsum[fl] + s_wt[slot];
            nx[j] = (float)s_to[slot];
        } else {
            sc[j] = bwlast + aw[j];
            nx[j] = (float)tg[j];          // state id < 2^24: exact in fp32
        }
    }
    const size_t obase = (size_t)b * VOCAB + v0;   // 16B-aligned (b*4KB + tid*16B)
    *reinterpret_cast<float4*>(out_scores + obase) = make_float4(sc[0], sc[1], sc[2], sc[3]);
    *reinterpret_cast<float4*>(out_next   + obase) = make_float4(nx[0], nx[1], nx[2], nx[3]);
}

extern "C" void kernel_launch(void* const* d_in, const int* in_sizes, int n_in,
                              void* d_out, int out_size, void* d_ws, size_t ws_size,
                              hipStream_t stream) {
    // setup_inputs() order:
    // 0 arcs_weights(f32) 1 backoff_weights(f32) 2 from_states(i32) 3 to_states(i32)
    // 4 ilabels(i32) 5 backoff_to_states(i32) 6 state_start_arcs(i32)
    // 7 state_end_arcs(i32) 8 state_order(i32) 9 states(i32)
    const float* arcs_weights    = (const float*)d_in[0];
    const float* backoff_weights = (const float*)d_in[1];
    const int*   to_states       = (const int*)d_in[3];
    const int*   ilabels         = (const int*)d_in[4];
    const int*   backoff_to      = (const int*)d_in[5];
    const int*   ssa             = (const int*)d_in[6];
    const int*   sea             = (const int*)d_in[7];
    const int*   states          = (const int*)d_in[9];
    const int B = in_sizes[9];

    float* out_scores = (float*)d_out;
    float* out_next   = out_scores + (size_t)B * VOCAB;

    ngram_advance<<<dim3(B), dim3(256), 0, stream>>>(
        arcs_weights, backoff_weights, to_states, ilabels, backoff_to,
        ssa, sea, states, out_scores, out_next);
}